// Round 7
// baseline (576.130 us; speedup 1.0000x reference)
//
#include <hip/hip_runtime.h>
#include <stdint.h>

#define N_PART   100000
#define N_FRAMES 500

typedef float f32x2 __attribute__((ext_vector_type(2)));

__device__ __forceinline__ uint32_t rotl32(uint32_t v, int d) {
    return (v << d) | (v >> (32 - d));
}

// JAX threefry2x32, 20 rounds, exact port of jax/_src/prng.py
#define TF_ROUND(r) { x0 += x1; x1 = rotl32(x1, (r)); x1 ^= x0; }

__device__ __forceinline__ void tf2x32(uint32_t k0, uint32_t k1,
                                       uint32_t x0, uint32_t x1,
                                       uint32_t &o0, uint32_t &o1) {
    const uint32_t k2 = k0 ^ k1 ^ 0x1BD11BDAu;
    x0 += k0; x1 += k1;
    TF_ROUND(13) TF_ROUND(15) TF_ROUND(26) TF_ROUND(6)
    x0 += k1; x1 += k2 + 1u;
    TF_ROUND(17) TF_ROUND(29) TF_ROUND(16) TF_ROUND(24)
    x0 += k2; x1 += k0 + 2u;
    TF_ROUND(13) TF_ROUND(15) TF_ROUND(26) TF_ROUND(6)
    x0 += k0; x1 += k1 + 3u;
    TF_ROUND(17) TF_ROUND(29) TF_ROUND(16) TF_ROUND(24)
    x0 += k1; x1 += k2 + 4u;
    TF_ROUND(13) TF_ROUND(15) TF_ROUND(26) TF_ROUND(6)
    x0 += k2; x1 += k0 + 5u;
    o0 = x0; o1 = x1;
}

// partitionable random_bits(key,32,shape): bits[idx] = o0^o1 of tf(key,(0,idx))
__device__ __forceinline__ float uniform_from_bits(uint32_t bits) {
    return __uint_as_float((bits >> 9) | 0x3f800000u) - 1.0f;
}

// Single kernel, both-branch eval: every threefry eval is independent of the
// chain state (counters 2n and 2n+1 computed every frame) -> no cross-frame
// dependency except a 2-op select. Pure issue-bound VALU; stores overlap free.
__global__ __launch_bounds__(256)
void hmm_kernel(const float* __restrict__ initial,
                const int* __restrict__ seed_ptr,
                float* __restrict__ out) {
    __shared__ uint2 skey[N_FRAMES];
    __shared__ float sp_;

    const int tid = threadIdx.x;
    const uint32_t seed_lo = (uint32_t)seed_ptr[0];

    // split(key(seed)) foldlike: ks = tf(key,(0,1)); keys[t] = tf(ks,(0,t))
    {
        uint32_t ks0, ks1;
        tf2x32(0u, seed_lo, 0u, 1u, ks0, ks1);
        for (int t = tid; t < N_FRAMES; t += 256) {
            uint32_t a, b;
            tf2x32(ks0, ks1, 0u, (uint32_t)t, a, b);
            skey[t] = make_uint2(a, b);
        }
    }
    if (tid == 0) {
        uint32_t kp0, kp1, b0, b1;
        tf2x32(0u, seed_lo, 0u, 0u, kp0, kp1);
        tf2x32(kp0, kp1, 0u, 0u, b0, b1);
        sp_ = uniform_from_bits(b0 ^ b1) * 0.001f;
    }
    __syncthreads();

    const int n = blockIdx.x * 256 + tid;
    if (n >= N_PART) return;

    const float p = sp_;                    // P(flip | s==1)
    const uint32_t base = 2u * (uint32_t)n;

    uint32_t s = (initial[2 * n + 1] > 0.5f) ? 1u : 0u;

    f32x2* __restrict__ outv = (f32x2*)out;

    #pragma unroll 2
    for (int t = 0; t < N_FRAMES; ++t) {
        const uint2 k = skey[t];            // single ds_read_b64
        uint32_t a0, a1, b0, b1;
        tf2x32(k.x, k.y, 0u, base,      a0, a1);   // branch from s=0 (u at 2n)
        tf2x32(k.x, k.y, 0u, base + 1u, b0, b1);   // branch from s=1 (u at 2n+1)
        const float u0 = uniform_from_bits(a0 ^ a1);
        const float u1 = uniform_from_bits(b0 ^ b1);
        const uint32_t next0 = (u0 < 0.2f) ? 1u : 0u;  // from s=0: flip if hit
        const uint32_t next1 = (u1 < p)    ? 0u : 1u;  // from s=1: flip if hit
        s = s ? next1 : next0;              // only serial carry (2 ops)
        f32x2 o;
        o.x = 1.0f - (float)s;
        o.y = (float)s;
        __builtin_nontemporal_store(o, &outv[(size_t)t * N_PART + n]);
    }
}

extern "C" void kernel_launch(void* const* d_in, const int* in_sizes, int n_in,
                              void* d_out, int out_size, void* d_ws, size_t ws_size,
                              hipStream_t stream) {
    const float* initial = (const float*)d_in[0];
    const int*   seed    = (const int*)d_in[1];
    float*       out     = (float*)d_out;

    const int block = 256;
    const int grid = (N_PART + block - 1) / block;   // 391 blocks, 1564 waves
    hmm_kernel<<<grid, block, 0, stream>>>(initial, seed, out);
}